// Round 5
// baseline (186.397 us; speedup 1.0000x reference)
//
#include <hip/hip_runtime.h>

typedef unsigned int uint;
typedef unsigned short ushort;

using bf16x8 = __attribute__((ext_vector_type(8))) short;
using f32x4  = __attribute__((ext_vector_type(4))) float;

// round-to-nearest-even fp32 -> bf16
__device__ __forceinline__ ushort f2b(float f) {
  union { float f; uint i; } v; v.f = f;
  uint r = (v.i + 0x7fffu + ((v.i >> 16) & 1u)) >> 16;
  return (ushort)r;
}
__device__ __forceinline__ bf16x8 ldfrag(const ushort* p) {
  union { uint4 u; bf16x8 v; } x; x.u = *(const uint4*)p; return x.v;
}

// =====================================================================
// Prep: fc1_w [128][54] fp32 -> ws[0..8191]   bf16 [128][64], k>=54 zero
//       out_w [128][128] fp32 -> ws[8192..]   bf16 [128][128]
// 96 blocks x 256 threads, one element each, fully coalesced.
// =====================================================================
__global__ __launch_bounds__(256) void prep_kernel(
    const float* __restrict__ fc1w, const float* __restrict__ outw,
    ushort* __restrict__ ws) {
  const int g = blockIdx.x * 256 + threadIdx.x;
  if (g < 8192) {
    const int row = g >> 6, k = g & 63;
    ws[g] = (k < 54) ? f2b(fc1w[row * 54 + k]) : (ushort)0;
  } else {
    const int idx = g - 8192;               // 0..16383
    ws[g] = f2b(outw[idx]);
  }
}

// =====================================================================
// Fused kernel: 256 threads = 4 waves = 256 samples/block; 512 blocks.
// Per thread: conv pipeline in registers -> h2 bf16 row in LDS.
// FC in FOUR M=64 slabs via 16x16x32 bf16 MFMA (wave wv owns one 16-row
// m-tile per slab); B-fragments read directly from L2-resident ws.
// LDS: h2A 36864 + tA 17408 = 54272 B -> 3 blocks/CU (12 waves/CU).
// =====================================================================
__global__ __launch_bounds__(256, 3) void fused_kernel(
    const float* __restrict__ x,
    const float* __restrict__ w1g, const float* __restrict__ b1g,
    const float* __restrict__ w2g, const float* __restrict__ b2g,
    const ushort* __restrict__ wsw,
    const float* __restrict__ fc1b, const float* __restrict__ outb,
    float* __restrict__ out) {
  __shared__ __align__(16) ushort h2A[256][72];  // [s][k], 2-way bank alias only
  __shared__ __align__(16) ushort tA[64][136];   // [s_local][j] per slab

  const int t = threadIdx.x;
  const int s0 = blockIdx.x * 256;
  const int lane = t & 63, wv = t >> 6;
  const int quad = lane >> 4, lm = lane & 15;

  // ---------------- conv pipeline (per thread = one sample) -------------
  {
    const float* xs = x + (size_t)(s0 + t) * 128;
    float xv[128];
#pragma unroll
    for (int i = 0; i < 32; ++i) {
      const float4 v = ((const float4*)xs)[i];
      xv[4 * i + 0] = v.x; xv[4 * i + 1] = v.y;
      xv[4 * i + 2] = v.z; xv[4 * i + 3] = v.w;
    }

    float w1[3][9], b1[3];
#pragma unroll
    for (int c = 0; c < 3; ++c) {
      b1[c] = b1g[c];
#pragma unroll
      for (int q = 0; q < 9; ++q) w1[c][q] = w1g[c * 9 + q];
    }

    float h1[3][6][6];
#pragma unroll
    for (int pr = 0; pr < 6; ++pr)
#pragma unroll
      for (int pc = 0; pc < 6; ++pc)
#pragma unroll
        for (int ch = 0; ch < 3; ++ch) {
          float m = -3.0e38f;
#pragma unroll
          for (int dr = 0; dr < 2; ++dr)
#pragma unroll
            for (int dc = 0; dc < 2; ++dc) {
              float a = 0.f;
#pragma unroll
              for (int ky = 0; ky < 3; ++ky)
#pragma unroll
                for (int kx = 0; kx < 3; ++kx) {
                  const int r = 2 * pr + dr + ky - 1;
                  const int c = 2 * pc + dc + kx - 1;
                  if (r >= 0 && r < 12 && c >= 0 && c < 12 && (12 * r + c) < 128)
                    a = fmaf(w1[ch][ky * 3 + kx], xv[12 * r + c], a);  // folds
                }
              m = fmaxf(m, a);
            }
          h1[ch][pr][pc] = fmaxf(m + b1[ch], 0.f);
        }

    float h2[54];
#pragma unroll
    for (int o = 0; o < 6; ++o) {
      float w2[27];
#pragma unroll
      for (int q = 0; q < 27; ++q) w2[q] = w2g[o * 27 + q];
      const float bo = b2g[o];
#pragma unroll
      for (int qr = 0; qr < 3; ++qr)
#pragma unroll
        for (int qc = 0; qc < 3; ++qc) {
          float m = -3.0e38f;
#pragma unroll
          for (int dr = 0; dr < 2; ++dr)
#pragma unroll
            for (int dc = 0; dc < 2; ++dc) {
              float a = 0.f;
#pragma unroll
              for (int i = 0; i < 3; ++i)
#pragma unroll
                for (int ky = 0; ky < 3; ++ky)
#pragma unroll
                  for (int kx = 0; kx < 3; ++kx) {
                    const int yy = 2 * qr + dr + ky - 1;
                    const int xx = 2 * qc + dc + kx - 1;
                    if (yy >= 0 && yy < 6 && xx >= 0 && xx < 6)  // folds
                      a = fmaf(w2[i * 9 + ky * 3 + kx], h1[i][yy][xx], a);
                  }
              m = fmaxf(m, a);
            }
          h2[o * 9 + qr * 3 + qc] = fmaxf(m + bo, 0.f);
        }
    }

    // pack to bf16, zero-pad k=54..63, write own LDS row (16B stores)
    uint pk[32];
#pragma unroll
    for (int q = 0; q < 27; ++q)
      pk[q] = (uint)f2b(h2[2 * q]) | ((uint)f2b(h2[2 * q + 1]) << 16);
#pragma unroll
    for (int q = 27; q < 32; ++q) pk[q] = 0u;
#pragma unroll
    for (int i = 0; i < 8; ++i) {
      uint4 v; v.x = pk[4 * i]; v.y = pk[4 * i + 1];
      v.z = pk[4 * i + 2]; v.w = pk[4 * i + 3];
      *(uint4*)&h2A[t][8 * i] = v;
    }
  }

  // biases in registers (per-lane column 16*nt+lm), L2-resident
  float fb1r[8], obr[8];
#pragma unroll
  for (int nt = 0; nt < 8; ++nt) {
    fb1r[nt] = fc1b[16 * nt + lm];
    obr[nt]  = outb[16 * nt + lm];
  }
  __syncthreads();  // h2A published

  const ushort* wsA = wsw;          // fc1_w bf16 [128][64]
  const ushort* wsB = wsw + 8192;   // out_w bf16 [128][128]

  // ---------------- FC via MFMA, four M=64 slabs ------------------------
  for (int h = 0; h < 4; ++h) {
    // phase1: t = relu(h2 @ fc1w^T + b)  rows 64h+16wv..+15, N=128, K=64
    f32x4 acc[8];
#pragma unroll
    for (int nt = 0; nt < 8; ++nt) acc[nt] = (f32x4){0.f, 0.f, 0.f, 0.f};

#pragma unroll
    for (int kk = 0; kk < 2; ++kk) {
      const int ko = kk * 32 + quad * 8;
      const bf16x8 a = ldfrag(&h2A[64 * h + 16 * wv + lm][ko]);
      bf16x8 b[8];
#pragma unroll
      for (int nt = 0; nt < 8; ++nt)
        b[nt] = ldfrag(wsA + (16 * nt + lm) * 64 + ko);
#pragma unroll
      for (int nt = 0; nt < 8; ++nt)
        acc[nt] = __builtin_amdgcn_mfma_f32_16x16x32_bf16(a, b[nt], acc[nt],
                                                          0, 0, 0);
    }

    // bias + relu -> bf16 -> tA (slab-local rows; C: col=lm, row=quad*4+r)
#pragma unroll
    for (int nt = 0; nt < 8; ++nt) {
      const int col = 16 * nt + lm;
#pragma unroll
      for (int r = 0; r < 4; ++r)
        tA[16 * wv + quad * 4 + r][col] = f2b(fmaxf(acc[nt][r] + fb1r[nt], 0.f));
    }
    __syncthreads();  // tA published

    // phase2: out = t @ outw^T + ob   K=128
    f32x4 acc2[8];
#pragma unroll
    for (int nt = 0; nt < 8; ++nt) acc2[nt] = (f32x4){0.f, 0.f, 0.f, 0.f};

#pragma unroll
    for (int kk = 0; kk < 4; ++kk) {
      const int ko = kk * 32 + quad * 8;
      const bf16x8 a = ldfrag(&tA[16 * wv + lm][ko]);
      bf16x8 b[8];
#pragma unroll
      for (int nt = 0; nt < 8; ++nt)
        b[nt] = ldfrag(wsB + (16 * nt + lm) * 128 + ko);
#pragma unroll
      for (int nt = 0; nt < 8; ++nt)
        acc2[nt] = __builtin_amdgcn_mfma_f32_16x16x32_bf16(a, b[nt], acc2[nt],
                                                           0, 0, 0);
    }

    // epilogue: + out_b, fp32 stores
#pragma unroll
    for (int nt = 0; nt < 8; ++nt) {
      const int col = 16 * nt + lm;
#pragma unroll
      for (int r = 0; r < 4; ++r) {
        const int srow = s0 + 64 * h + 16 * wv + quad * 4 + r;
        out[(size_t)srow * 128 + col] = acc2[nt][r] + obr[nt];
      }
    }
    __syncthreads();  // tA reads done before next slab overwrites
  }
}

extern "C" void kernel_launch(void* const* d_in, const int* in_sizes, int n_in,
                              void* d_out, int out_size, void* d_ws, size_t ws_size,
                              hipStream_t stream) {
  const float* x    = (const float*)d_in[0];
  const float* w1   = (const float*)d_in[1];
  const float* b1   = (const float*)d_in[2];
  const float* w2   = (const float*)d_in[3];
  const float* b2   = (const float*)d_in[4];
  const float* fc1w = (const float*)d_in[5];
  const float* fc1b = (const float*)d_in[6];
  const float* outw = (const float*)d_in[7];
  const float* outb = (const float*)d_in[8];
  float* outp = (float*)d_out;
  ushort* ws  = (ushort*)d_ws;   // bf16 weights: 48 KB

  const int N = in_sizes[0] / 128;   // 131072

  prep_kernel<<<96, 256, 0, stream>>>(fc1w, outw, ws);
  fused_kernel<<<N / 256, 256, 0, stream>>>(x, w1, b1, w2, b2, ws,
                                            fc1b, outb, outp);
}

// Round 6
// 171.070 us; speedup vs baseline: 1.0896x; 1.0896x over previous
//
#include <hip/hip_runtime.h>

typedef unsigned int uint;
typedef unsigned short ushort;

using bf16x8 = __attribute__((ext_vector_type(8))) short;
using f32x4  = __attribute__((ext_vector_type(4))) float;

// round-to-nearest-even fp32 -> bf16
__device__ __forceinline__ ushort f2b(float f) {
  union { float f; uint i; } v; v.f = f;
  uint r = (v.i + 0x7fffu + ((v.i >> 16) & 1u)) >> 16;
  return (ushort)r;
}
__device__ __forceinline__ bf16x8 ldfrag(const ushort* p) {
  union { uint4 u; bf16x8 v; } x; x.u = *(const uint4*)p; return x.v;
}

// =====================================================================
// Prep: fc1_w [128][54] fp32 -> ws[0..8191]   bf16 [128][64], k>=54 zero
//       out_w [128][128] fp32 -> ws[8192..]   bf16 [128][128]
// 96 blocks x 256 threads, one element each, fully coalesced.
// =====================================================================
__global__ __launch_bounds__(256) void prep_kernel(
    const float* __restrict__ fc1w, const float* __restrict__ outw,
    ushort* __restrict__ ws) {
  const int g = blockIdx.x * 256 + threadIdx.x;
  if (g < 8192) {
    const int row = g >> 6, k = g & 63;
    ws[g] = (k < 54) ? f2b(fc1w[row * 54 + k]) : (ushort)0;
  } else {
    ws[g] = f2b(outw[g - 8192]);
  }
}

// =====================================================================
// Fused kernel: 256 threads = 4 waves = 256 samples/block; 512 blocks
// (2 blocks/CU — grid-capped). conv per thread in registers; conv2
// OUTER LOOP ROLLED over output channel o (6x code-size cut vs full
// unroll; per-o results go straight to LDS via ds_write_b16, keeping
// all register arrays statically indexed -> no scratch).
// FC in two M=128 halves via 16x16x32 bf16 MFMA; B-fragments from
// L2-resident ws. LDS: h2A 36864 + tA 34816 = 71680 B.
// launch_bounds(256,2): round-4 evidence = clean 128-VGPR alloc,
// (256,3) caused scratch spill of xv[128] (FETCH +80 MB).
// =====================================================================
__global__ __launch_bounds__(256, 2) void fused_kernel(
    const float* __restrict__ x,
    const float* __restrict__ w1g, const float* __restrict__ b1g,
    const float* __restrict__ w2g, const float* __restrict__ b2g,
    const ushort* __restrict__ wsw,
    const float* __restrict__ fc1b, const float* __restrict__ outb,
    float* __restrict__ out) {
  __shared__ __align__(16) ushort h2A[256][72];   // [s][k] bf16
  __shared__ __align__(16) ushort tA[128][136];   // [s][j] bf16 per half

  const int t = threadIdx.x;
  const int s0 = blockIdx.x * 256;
  const int lane = t & 63, wv = t >> 6;
  const int quad = lane >> 4, lm = lane & 15;

  // ---------------- conv pipeline (per thread = one sample) -------------
  {
    const float* xs = x + (size_t)(s0 + t) * 128;
    float xv[128];
#pragma unroll
    for (int i = 0; i < 32; ++i) {
      const float4 v = ((const float4*)xs)[i];
      xv[4 * i + 0] = v.x; xv[4 * i + 1] = v.y;
      xv[4 * i + 2] = v.z; xv[4 * i + 3] = v.w;
    }

    float w1[3][9], b1[3];
#pragma unroll
    for (int c = 0; c < 3; ++c) {
      b1[c] = b1g[c];
#pragma unroll
      for (int q = 0; q < 9; ++q) w1[c][q] = w1g[c * 9 + q];
    }

    // conv1 + pool + relu (fully unrolled; xv indices all compile-time)
    float h1[3][6][6];
#pragma unroll
    for (int pr = 0; pr < 6; ++pr)
#pragma unroll
      for (int pc = 0; pc < 6; ++pc)
#pragma unroll
        for (int ch = 0; ch < 3; ++ch) {
          float m = -3.0e38f;
#pragma unroll
          for (int dr = 0; dr < 2; ++dr)
#pragma unroll
            for (int dc = 0; dc < 2; ++dc) {
              float a = 0.f;
#pragma unroll
              for (int ky = 0; ky < 3; ++ky)
#pragma unroll
                for (int kx = 0; kx < 3; ++kx) {
                  const int r = 2 * pr + dr + ky - 1;
                  const int c = 2 * pc + dc + kx - 1;
                  if (r >= 0 && r < 12 && c >= 0 && c < 12 && (12 * r + c) < 128)
                    a = fmaf(w1[ch][ky * 3 + kx], xv[12 * r + c], a);  // folds
                }
              m = fmaxf(m, a);
            }
          h1[ch][pr][pc] = fmaxf(m + b1[ch], 0.f);
        }

    // conv2 + pool + relu, ROLLED over o; outputs -> LDS ds_write_b16.
    // h1 indices stay compile-time (only o is runtime) -> no spill.
#pragma unroll 1
    for (int o = 0; o < 6; ++o) {
      float w2[27];
#pragma unroll
      for (int q = 0; q < 27; ++q) w2[q] = w2g[o * 27 + q];
      const float bo = b2g[o];
#pragma unroll
      for (int qr = 0; qr < 3; ++qr)
#pragma unroll
        for (int qc = 0; qc < 3; ++qc) {
          float m = -3.0e38f;
#pragma unroll
          for (int dr = 0; dr < 2; ++dr)
#pragma unroll
            for (int dc = 0; dc < 2; ++dc) {
              float a = 0.f;
#pragma unroll
              for (int i = 0; i < 3; ++i)
#pragma unroll
                for (int ky = 0; ky < 3; ++ky)
#pragma unroll
                  for (int kx = 0; kx < 3; ++kx) {
                    const int yy = 2 * qr + dr + ky - 1;
                    const int xx = 2 * qc + dc + kx - 1;
                    if (yy >= 0 && yy < 6 && xx >= 0 && xx < 6)  // folds
                      a = fmaf(w2[i * 9 + ky * 3 + kx], h1[i][yy][xx], a);
                  }
              m = fmaxf(m, a);
            }
          h2A[t][o * 9 + qr * 3 + qc] = f2b(fmaxf(m + bo, 0.f));
        }
    }
    // zero-pad k=54..63 (offset 108 B: dword-aligned)
    uint* pz = (uint*)&h2A[t][54];
#pragma unroll
    for (int q = 0; q < 5; ++q) pz[q] = 0u;
  }

  // biases into registers (per-lane column 16*nt+lm)
  float fb1r[8], obr[8];
#pragma unroll
  for (int nt = 0; nt < 8; ++nt) {
    fb1r[nt] = fc1b[16 * nt + lm];
    obr[nt]  = outb[16 * nt + lm];
  }
  __syncthreads();  // h2A published

  const ushort* wsA = wsw;          // fc1_w bf16 [128][64]
  const ushort* wsB = wsw + 8192;   // out_w bf16 [128][128]

  // ---------------- FC via MFMA, two M=128 halves -----------------------
  for (int h = 0; h < 2; ++h) {
    // phase1: t = relu(h2 @ fc1w^T + b)  M=128 K=64 N=128
    f32x4 acc[2][8];
#pragma unroll
    for (int mt = 0; mt < 2; ++mt)
#pragma unroll
      for (int nt = 0; nt < 8; ++nt) acc[mt][nt] = (f32x4){0.f, 0.f, 0.f, 0.f};

#pragma unroll
    for (int kk = 0; kk < 2; ++kk) {
      const int ko = kk * 32 + quad * 8;
      bf16x8 a[2], b[8];
#pragma unroll
      for (int mt = 0; mt < 2; ++mt)
        a[mt] = ldfrag(&h2A[128 * h + 32 * wv + 16 * mt + lm][ko]);
#pragma unroll
      for (int nt = 0; nt < 8; ++nt)
        b[nt] = ldfrag(wsA + (16 * nt + lm) * 64 + ko);
#pragma unroll
      for (int mt = 0; mt < 2; ++mt)
#pragma unroll
        for (int nt = 0; nt < 8; ++nt)
          acc[mt][nt] = __builtin_amdgcn_mfma_f32_16x16x32_bf16(
              a[mt], b[nt], acc[mt][nt], 0, 0, 0);
    }

    // bias + relu -> bf16 -> tA (C layout: col=lm, row=quad*4+r)
#pragma unroll
    for (int mt = 0; mt < 2; ++mt)
#pragma unroll
      for (int nt = 0; nt < 8; ++nt) {
        const int col = 16 * nt + lm;
#pragma unroll
        for (int r = 0; r < 4; ++r) {
          const int row = 32 * wv + 16 * mt + quad * 4 + r;
          tA[row][col] = f2b(fmaxf(acc[mt][nt][r] + fb1r[nt], 0.f));
        }
      }
    __syncthreads();  // tA published (and prior phase2 reads finished)

    // phase2: out = t @ outw^T + ob  M=128 K=128 N=128
    f32x4 acc2[2][8];
#pragma unroll
    for (int mt = 0; mt < 2; ++mt)
#pragma unroll
      for (int nt = 0; nt < 8; ++nt) acc2[mt][nt] = (f32x4){0.f, 0.f, 0.f, 0.f};

#pragma unroll
    for (int kk = 0; kk < 4; ++kk) {
      const int ko = kk * 32 + quad * 8;
      bf16x8 a[2], b[8];
#pragma unroll
      for (int mt = 0; mt < 2; ++mt)
        a[mt] = ldfrag(&tA[32 * wv + 16 * mt + lm][ko]);
#pragma unroll
      for (int nt = 0; nt < 8; ++nt)
        b[nt] = ldfrag(wsB + (16 * nt + lm) * 128 + ko);
#pragma unroll
      for (int mt = 0; mt < 2; ++mt)
#pragma unroll
        for (int nt = 0; nt < 8; ++nt)
          acc2[mt][nt] = __builtin_amdgcn_mfma_f32_16x16x32_bf16(
              a[mt], b[nt], acc2[mt][nt], 0, 0, 0);
    }

    // epilogue: + out_b, fp32 stores
#pragma unroll
    for (int mt = 0; mt < 2; ++mt)
#pragma unroll
      for (int nt = 0; nt < 8; ++nt) {
        const int col = 16 * nt + lm;
#pragma unroll
        for (int r = 0; r < 4; ++r) {
          const int srow = s0 + 128 * h + 32 * wv + 16 * mt + quad * 4 + r;
          out[(size_t)srow * 128 + col] = acc2[mt][nt][r] + obr[nt];
        }
      }
    __syncthreads();  // tA reads done before next-half overwrite
  }
}

extern "C" void kernel_launch(void* const* d_in, const int* in_sizes, int n_in,
                              void* d_out, int out_size, void* d_ws, size_t ws_size,
                              hipStream_t stream) {
  const float* x    = (const float*)d_in[0];
  const float* w1   = (const float*)d_in[1];
  const float* b1   = (const float*)d_in[2];
  const float* w2   = (const float*)d_in[3];
  const float* b2   = (const float*)d_in[4];
  const float* fc1w = (const float*)d_in[5];
  const float* fc1b = (const float*)d_in[6];
  const float* outw = (const float*)d_in[7];
  const float* outb = (const float*)d_in[8];
  float* outp = (float*)d_out;
  ushort* ws  = (ushort*)d_ws;   // bf16 weights: 48 KB

  const int N = in_sizes[0] / 128;   // 131072

  prep_kernel<<<96, 256, 0, stream>>>(fc1w, outw, ws);
  fused_kernel<<<N / 256, 256, 0, stream>>>(x, w1, b1, w2, b2, ws,
                                            fc1b, outb, outp);
}